// Round 6
// baseline (225.554 us; speedup 1.0000x reference)
//
#include <hip/hip_runtime.h>
#include <stdint.h>

#define N_NODES 50000
#define N_EDGES 800000
#define IN_DIM  128
#define HID_DIM 64
#define OUT_DIM 64

#define SCAN_BLOCKS ((N_NODES + 255) / 256)   // 196

// ---------------------------------------------------------------------------
// k_zero: deg[i] = 0
// ---------------------------------------------------------------------------
__global__ void k_zero(int* __restrict__ deg, int n) {
    int i = blockIdx.x * blockDim.x + threadIdx.x;
    if (i < n) deg[i] = 0;
}

// ---------------------------------------------------------------------------
// k_hist: deg[dst]++ per edge (int atomics)
// ---------------------------------------------------------------------------
__global__ void k_hist(const int* __restrict__ ei, int* __restrict__ deg) {
    int e = blockIdx.x * blockDim.x + threadIdx.x;
    if (e < N_EDGES) atomicAdd(&deg[ei[N_EDGES + e]], 1);
}

// ---------------------------------------------------------------------------
// k_bsum: bsum[b] = sum of deg over block b's 256 nodes (wave shuffle reduce)
// ---------------------------------------------------------------------------
__global__ __launch_bounds__(256) void k_bsum(const int* __restrict__ deg,
                                              int* __restrict__ bsum) {
    int b = blockIdx.x, t = threadIdx.x;
    int node = b * 256 + t;
    int d = (node < N_NODES) ? deg[node] : 0;
    for (int o = 32; o > 0; o >>= 1) d += __shfl_down(d, o, 64);
    __shared__ int ws[4];
    int wid = t >> 6, lane = t & 63;
    if (lane == 0) ws[wid] = d;
    __syncthreads();
    if (t == 0) bsum[b] = ws[0] + ws[1] + ws[2] + ws[3];
}

// ---------------------------------------------------------------------------
// k_scan2: per-block exclusive scan -> rowstart & cur.  Also emits
// dinv[i] = rsqrt(deg[i]+1) (free: deg already in registers).
// ---------------------------------------------------------------------------
__global__ __launch_bounds__(256) void k_scan2(const int* __restrict__ deg,
                                               const int* __restrict__ bsum,
                                               int* __restrict__ rowstart,
                                               int* __restrict__ cur,
                                               float* __restrict__ dinv) {
    int b = blockIdx.x, t = threadIdx.x;
    int node = b * 256 + t;
    int wid = t >> 6, lane = t & 63;

    // ---- block offset: sum of preceding block sums ----
    int partial = 0;
    for (int i = t; i < b; i += 256) partial += bsum[i];
    for (int o = 32; o > 0; o >>= 1) partial += __shfl_down(partial, o, 64);
    __shared__ int ws[4];
    __shared__ int sh_off;
    if (lane == 0) ws[wid] = partial;
    __syncthreads();
    if (t == 0) sh_off = ws[0] + ws[1] + ws[2] + ws[3];
    __syncthreads();
    int off = sh_off;

    // ---- local inclusive scan (wave shuffle + cross-wave LDS) ----
    int d = (node < N_NODES) ? deg[node] : 0;
    int incl = d;
    for (int o = 1; o < 64; o <<= 1) {
        int v = __shfl_up(incl, o, 64);
        if (lane >= o) incl += v;
    }
    __shared__ int wtot[4];
    if (lane == 63) wtot[wid] = incl;
    __syncthreads();
    int woff = 0;
    for (int w = 0; w < wid; ++w) woff += wtot[w];

    int excl = off + woff + incl - d;
    if (node < N_NODES) {
        rowstart[node] = excl;
        cur[node] = excl;
        dinv[node] = rsqrtf((float)d + 1.0f);
        if (node == N_NODES - 1) rowstart[N_NODES] = excl + d;
    }
}

// ---------------------------------------------------------------------------
// k_fill: scatter edges into CSR slots; record = src only (4B).  Norm is
// factorized out: hs = h*dinv is prescaled, gather post-scales by dinv[dst].
// ---------------------------------------------------------------------------
__global__ void k_fill(const int* __restrict__ ei, int* __restrict__ cur,
                       int* __restrict__ edata) {
    int e = blockIdx.x * blockDim.x + threadIdx.x;
    if (e >= N_EDGES) return;
    int s = ei[e];
    int d = ei[N_EDGES + e];
    int pos = atomicAdd(&cur[d], 1);
    edata[pos] = s;
}

// ---------------------------------------------------------------------------
// k_gemm3: HS[n,64] = (X[n,K] @ W[K,64]) * dinv[row].
// 64 rows x 64 cols per block, 256 threads = 16 col-quads x 16 row-groups,
// thread tile = 4 rows x 4 cols. Only W staged in LDS; X read directly from
// global (16 same-address lanes merge into one transaction).
// ---------------------------------------------------------------------------
__device__ __forceinline__ void fma4(float4& acc, const float4& xv,
                                     const float4& w0, const float4& w1,
                                     const float4& w2, const float4& w3) {
    acc.x += xv.x * w0.x + xv.y * w1.x + xv.z * w2.x + xv.w * w3.x;
    acc.y += xv.x * w0.y + xv.y * w1.y + xv.z * w2.y + xv.w * w3.y;
    acc.z += xv.x * w0.z + xv.y * w1.z + xv.z * w2.z + xv.w * w3.z;
    acc.w += xv.x * w0.w + xv.y * w1.w + xv.z * w2.w + xv.w * w3.w;
}

__device__ __forceinline__ void scale4(float4& a, float s) {
    a.x *= s; a.y *= s; a.z *= s; a.w *= s;
}

template <int K>
__global__ __launch_bounds__(256) void k_gemm3(const float* __restrict__ X,
                                               const float* __restrict__ W,
                                               const float* __restrict__ dinv,
                                               float* __restrict__ HS, int n) {
    constexpr int QK = K / 4;                 // float4 quads per row
    __shared__ float4 Ws[K * 16];             // [K][64] as quads
    const int tid = threadIdx.x;
    const int row0 = blockIdx.x * 64;

    for (int f = tid; f < K * 16; f += 256) Ws[f] = ((const float4*)W)[f];
    __syncthreads();

    const int c4 = tid & 15;                  // col quad
    const int r0 = row0 + ((tid >> 4) << 2);  // first of this thread's 4 rows
    const float4* Xq = (const float4*)X;

    float4 a0 = make_float4(0.f, 0.f, 0.f, 0.f);
    float4 a1 = a0, a2 = a0, a3 = a0;

    if (r0 + 3 < n) {                         // fast path (all but last block)
        const float4* xp0 = Xq + (size_t)r0 * QK;
        const float4* xp1 = xp0 + QK;
        const float4* xp2 = xp1 + QK;
        const float4* xp3 = xp2 + QK;
#pragma unroll 4
        for (int k4 = 0; k4 < QK; ++k4) {
            const float4 x0 = xp0[k4];
            const float4 x1 = xp1[k4];
            const float4 x2 = xp2[k4];
            const float4 x3 = xp3[k4];
            const float4 w0 = Ws[(k4 * 4 + 0) * 16 + c4];
            const float4 w1 = Ws[(k4 * 4 + 1) * 16 + c4];
            const float4 w2 = Ws[(k4 * 4 + 2) * 16 + c4];
            const float4 w3 = Ws[(k4 * 4 + 3) * 16 + c4];
            fma4(a0, x0, w0, w1, w2, w3);
            fma4(a1, x1, w0, w1, w2, w3);
            fma4(a2, x2, w0, w1, w2, w3);
            fma4(a3, x3, w0, w1, w2, w3);
        }
        const float4 dv = ((const float4*)dinv)[r0 >> 2];   // r0 % 4 == 0
        scale4(a0, dv.x); scale4(a1, dv.y); scale4(a2, dv.z); scale4(a3, dv.w);
        ((float4*)HS)[(size_t)(r0 + 0) * 16 + c4] = a0;
        ((float4*)HS)[(size_t)(r0 + 1) * 16 + c4] = a1;
        ((float4*)HS)[(size_t)(r0 + 2) * 16 + c4] = a2;
        ((float4*)HS)[(size_t)(r0 + 3) * 16 + c4] = a3;
    } else {                                  // guarded tail (last block only)
        const float4 z = make_float4(0.f, 0.f, 0.f, 0.f);
        for (int k4 = 0; k4 < QK; ++k4) {
            const float4 x0 = (r0 + 0 < n) ? Xq[(size_t)(r0 + 0) * QK + k4] : z;
            const float4 x1 = (r0 + 1 < n) ? Xq[(size_t)(r0 + 1) * QK + k4] : z;
            const float4 x2 = (r0 + 2 < n) ? Xq[(size_t)(r0 + 2) * QK + k4] : z;
            const float4 x3 = (r0 + 3 < n) ? Xq[(size_t)(r0 + 3) * QK + k4] : z;
            const float4 w0 = Ws[(k4 * 4 + 0) * 16 + c4];
            const float4 w1 = Ws[(k4 * 4 + 1) * 16 + c4];
            const float4 w2 = Ws[(k4 * 4 + 2) * 16 + c4];
            const float4 w3 = Ws[(k4 * 4 + 3) * 16 + c4];
            fma4(a0, x0, w0, w1, w2, w3);
            fma4(a1, x1, w0, w1, w2, w3);
            fma4(a2, x2, w0, w1, w2, w3);
            fma4(a3, x3, w0, w1, w2, w3);
        }
        if (r0 + 0 < n) { scale4(a0, dinv[r0 + 0]); ((float4*)HS)[(size_t)(r0 + 0) * 16 + c4] = a0; }
        if (r0 + 1 < n) { scale4(a1, dinv[r0 + 1]); ((float4*)HS)[(size_t)(r0 + 1) * 16 + c4] = a1; }
        if (r0 + 2 < n) { scale4(a2, dinv[r0 + 2]); ((float4*)HS)[(size_t)(r0 + 2) * 16 + c4] = a2; }
        if (r0 + 3 < n) { scale4(a3, dinv[r0 + 3]); ((float4*)HS)[(size_t)(r0 + 3) * 16 + c4] = a3; }
    }
}

// ---------------------------------------------------------------------------
// k_gather: per-node CSR aggregation on prescaled hs.
// out[i] = dinv[i] * (sum_{j in N(i)} hs[j] + hs[i]) + b   (+ ReLU)
// ---------------------------------------------------------------------------
template <bool RELU>
__global__ __launch_bounds__(256) void k_gather(const int* __restrict__ rowstart,
                                                const int* __restrict__ edata,
                                                const float* __restrict__ hs,
                                                const float* __restrict__ dinv,
                                                const float* __restrict__ bias,
                                                float* __restrict__ out) {
    int node = blockIdx.x * 16 + (threadIdx.x >> 4);
    int lane = threadIdx.x & 15;
    if (node >= N_NODES) return;

    int start = rowstart[node];
    int end   = rowstart[node + 1];

    float4 acc = make_float4(0.f, 0.f, 0.f, 0.f);
    for (int j = start; j < end; ++j) {
        int s = edata[j];                         // broadcast across 16 lanes
        const float4 v = *reinterpret_cast<const float4*>(&hs[(size_t)s * 64 + lane * 4]);
        acc.x += v.x;
        acc.y += v.y;
        acc.z += v.z;
        acc.w += v.w;
    }
    // self loop (hs already carries one dinv factor)
    const float4 hv = *reinterpret_cast<const float4*>(&hs[(size_t)node * 64 + lane * 4]);
    acc.x += hv.x; acc.y += hv.y; acc.z += hv.z; acc.w += hv.w;

    const float di = dinv[node];
    const float4 bv = *reinterpret_cast<const float4*>(&bias[lane * 4]);
    acc.x = acc.x * di + bv.x;
    acc.y = acc.y * di + bv.y;
    acc.z = acc.z * di + bv.z;
    acc.w = acc.w * di + bv.w;
    if (RELU) {
        acc.x = fmaxf(acc.x, 0.f);
        acc.y = fmaxf(acc.y, 0.f);
        acc.z = fmaxf(acc.z, 0.f);
        acc.w = fmaxf(acc.w, 0.f);
    }
    *reinterpret_cast<float4*>(&out[(size_t)node * 64 + lane * 4]) = acc;
}

extern "C" void kernel_launch(void* const* d_in, const int* in_sizes, int n_in,
                              void* d_out, int out_size, void* d_ws, size_t ws_size,
                              hipStream_t stream) {
    const float* x  = (const float*)d_in[0];
    const int*   ei = (const int*)d_in[1];    // [2, N_EDGES] int32
    const float* W1 = (const float*)d_in[2];
    const float* b1 = (const float*)d_in[3];
    const float* W2 = (const float*)d_in[4];
    const float* b2 = (const float*)d_in[5];
    float* out = (float*)d_out;

    // Workspace carve-up (dinv kept 16B-aligned for float4 loads):
    //   deg[N] | rowstart[N+4] | cur[N] | dinv[N] | bsum[200] | edata[E]*4B |
    //   hs[N*64] | a1[N*64]   ~= 30 MB
    int*   deg      = (int*)d_ws;
    int*   rowstart = deg + N_NODES;
    int*   cur      = rowstart + (N_NODES + 4);          // padded for alignment
    float* dinv     = (float*)(cur + N_NODES);           // offset 150004 (16B-aligned)
    int*   bsum     = (int*)(dinv + N_NODES);
    int*   edata    = bsum + 200;
    float* hs       = (float*)(edata + N_EDGES);
    float* a1       = hs + (size_t)N_NODES * 64;

    // --- CSR build ---
    k_zero<<<(N_NODES + 255) / 256, 256, 0, stream>>>(deg, N_NODES);
    k_hist<<<(N_EDGES + 255) / 256, 256, 0, stream>>>(ei, deg);
    k_bsum<<<SCAN_BLOCKS, 256, 0, stream>>>(deg, bsum);
    k_scan2<<<SCAN_BLOCKS, 256, 0, stream>>>(deg, bsum, rowstart, cur, dinv);
    k_fill<<<(N_EDGES + 255) / 256, 256, 0, stream>>>(ei, cur, edata);

    // --- layer 1 ---
    k_gemm3<IN_DIM><<<(N_NODES + 63) / 64, 256, 0, stream>>>(x, W1, dinv, hs, N_NODES);
    k_gather<true><<<(N_NODES + 15) / 16, 256, 0, stream>>>(rowstart, edata, hs, dinv, b1, a1);

    // --- layer 2 ---
    k_gemm3<HID_DIM><<<(N_NODES + 63) / 64, 256, 0, stream>>>(a1, W2, dinv, hs, N_NODES);
    k_gather<false><<<(N_NODES + 15) / 16, 256, 0, stream>>>(rowstart, edata, hs, dinv, b2, out);
}

// Round 7
// 175.314 us; speedup vs baseline: 1.2866x; 1.2866x over previous
//
#include <hip/hip_runtime.h>
#include <stdint.h>

#define N_NODES 50000
#define N_EDGES 800000
#define IN_DIM  128
#define HID_DIM 64
#define OUT_DIM 64

#define NPB     256                         // partition blocks
#define EPB     (N_EDGES / NPB)             // 3125 edges per block (exact)
#define BSH     9                           // bucket shift: 512 nodes/bucket
#define NB      ((N_NODES + 511) >> BSH)    // 98 buckets

// ---------------------------------------------------------------------------
// k_bhist: per-(block,bucket) histogram of dst. histT[bkt*NPB + blk].
// ---------------------------------------------------------------------------
__global__ __launch_bounds__(256) void k_bhist(const int* __restrict__ ei,
                                               int* __restrict__ histT) {
    __shared__ int hist[NB];
    const int blk = blockIdx.x, tid = threadIdx.x;
    if (tid < NB) hist[tid] = 0;
    __syncthreads();
    const int e0 = blk * EPB;
    for (int e = e0 + tid; e < e0 + EPB; e += 256)
        atomicAdd(&hist[ei[N_EDGES + e] >> BSH], 1);
    __syncthreads();
    if (tid < NB) histT[tid * NPB + blk] = hist[tid];
}

// ---------------------------------------------------------------------------
// k_bscan: single-block exclusive scan (in place) of histT[NB*NPB] in
// bucket-major order; emits bucketstart[NB+1].
// ---------------------------------------------------------------------------
__global__ __launch_bounds__(256) void k_bscan(int* __restrict__ histT,
                                               int* __restrict__ bucketstart) {
    const int t = threadIdx.x;
    const int CH = (NB * NPB) / 256;        // 98 contiguous elements per thread
    const int base = t * CH;
    int s = 0;
#pragma unroll 7
    for (int i = 0; i < CH; ++i) s += histT[base + i];

    // inclusive shuffle scan of 256 partials
    int wid = t >> 6, lane = t & 63;
    int incl = s;
    for (int o = 1; o < 64; o <<= 1) {
        int v = __shfl_up(incl, o, 64);
        if (lane >= o) incl += v;
    }
    __shared__ int wt[4];
    if (lane == 63) wt[wid] = incl;
    __syncthreads();
    int woff = 0;
    for (int w = 0; w < wid; ++w) woff += wt[w];
    int excl = woff + incl - s;

#pragma unroll 7
    for (int i = 0; i < CH; ++i) {
        int v = histT[base + i];
        histT[base + i] = excl;
        excl += v;
    }
    __syncthreads();
    if (t < NB) bucketstart[t] = histT[t * NPB];
    if (t == 0) bucketstart[NB] = N_EDGES;
}

// ---------------------------------------------------------------------------
// k_part: re-stream edges; write rec = src | dlo<<16 into this block's
// reserved contiguous chunk of each bucket (coalesced-ish, XCD-friendly).
// ---------------------------------------------------------------------------
__global__ __launch_bounds__(256) void k_part(const int* __restrict__ ei,
                                              const int* __restrict__ histT,
                                              int* __restrict__ brec) {
    __shared__ int cursor[NB];
    const int blk = blockIdx.x, tid = threadIdx.x;
    if (tid < NB) cursor[tid] = histT[tid * NPB + blk];
    __syncthreads();
    const int e0 = blk * EPB;
    for (int e = e0 + tid; e < e0 + EPB; e += 256) {
        int s = ei[e];
        int d = ei[N_EDGES + e];
        int b = d >> BSH;
        int pos = atomicAdd(&cursor[b], 1);
        brec[pos] = s | ((d & 511) << 16);
    }
}

// ---------------------------------------------------------------------------
// k_csr: one block per bucket (512 nodes).  Counts per-node deg in LDS,
// block-scans to per-node offsets, emits rowstart & dinv (coalesced), then
// scatters final edata (src only) — whole CSR region written by ONE wg/XCD.
// ---------------------------------------------------------------------------
__global__ __launch_bounds__(256) void k_csr(const int* __restrict__ brec,
                                             const int* __restrict__ bucketstart,
                                             int* __restrict__ rowstart,
                                             float* __restrict__ dinv,
                                             int* __restrict__ edata) {
    __shared__ int deg[512];
    __shared__ int segoff[512];
    __shared__ int wt[4];
    const int b = blockIdx.x, tid = threadIdx.x;
    const int lo = b << BSH;
    const int cstart = bucketstart[b];
    const int cend   = bucketstart[b + 1];

    deg[tid] = 0;
    deg[tid + 256] = 0;
    __syncthreads();

    // pass 1: per-node degree
    for (int j = cstart + tid; j < cend; j += 256)
        atomicAdd(&deg[brec[j] >> 16], 1);
    __syncthreads();

    // block exclusive scan over 512 degs (2 per thread)
    const int i0 = tid << 1;
    const int d0 = deg[i0], d1 = deg[i0 + 1];
    const int s = d0 + d1;
    int wid = tid >> 6, lane = tid & 63;
    int incl = s;
    for (int o = 1; o < 64; o <<= 1) {
        int v = __shfl_up(incl, o, 64);
        if (lane >= o) incl += v;
    }
    if (lane == 63) wt[wid] = incl;
    __syncthreads();
    int woff = 0;
    for (int w = 0; w < wid; ++w) woff += wt[w];
    const int excl = woff + incl - s;

    segoff[i0]     = excl;
    segoff[i0 + 1] = excl + d0;

    // emit rowstart + dinv (coalesced; guard the ragged last bucket)
    if (lo + i0 < N_NODES) {
        rowstart[lo + i0] = cstart + excl;
        dinv[lo + i0] = rsqrtf((float)d0 + 1.0f);
    }
    if (lo + i0 + 1 < N_NODES) {
        rowstart[lo + i0 + 1] = cstart + excl + d0;
        dinv[lo + i0 + 1] = rsqrtf((float)d1 + 1.0f);
    }
    if (b == NB - 1 && tid == 0) rowstart[N_NODES] = cend;
    __syncthreads();

    // pass 2: scatter records into final CSR slots (destroys segoff)
    for (int j = cstart + tid; j < cend; j += 256) {
        int rec = brec[j];
        int pos = cstart + atomicAdd(&segoff[rec >> 16], 1);
        edata[pos] = rec & 0xFFFF;
    }
}

// ---------------------------------------------------------------------------
// k_gemm3: HS[n,64] = (X[n,K] @ W[K,64]) * dinv[row].
// ---------------------------------------------------------------------------
__device__ __forceinline__ void fma4(float4& acc, const float4& xv,
                                     const float4& w0, const float4& w1,
                                     const float4& w2, const float4& w3) {
    acc.x += xv.x * w0.x + xv.y * w1.x + xv.z * w2.x + xv.w * w3.x;
    acc.y += xv.x * w0.y + xv.y * w1.y + xv.z * w2.y + xv.w * w3.y;
    acc.z += xv.x * w0.z + xv.y * w1.z + xv.z * w2.z + xv.w * w3.z;
    acc.w += xv.x * w0.w + xv.y * w1.w + xv.z * w2.w + xv.w * w3.w;
}

__device__ __forceinline__ void scale4(float4& a, float s) {
    a.x *= s; a.y *= s; a.z *= s; a.w *= s;
}

template <int K>
__global__ __launch_bounds__(256) void k_gemm3(const float* __restrict__ X,
                                               const float* __restrict__ W,
                                               const float* __restrict__ dinv,
                                               float* __restrict__ HS, int n) {
    constexpr int QK = K / 4;
    __shared__ float4 Ws[K * 16];
    const int tid = threadIdx.x;
    const int row0 = blockIdx.x * 64;

    for (int f = tid; f < K * 16; f += 256) Ws[f] = ((const float4*)W)[f];
    __syncthreads();

    const int c4 = tid & 15;
    const int r0 = row0 + ((tid >> 4) << 2);
    const float4* Xq = (const float4*)X;

    float4 a0 = make_float4(0.f, 0.f, 0.f, 0.f);
    float4 a1 = a0, a2 = a0, a3 = a0;

    if (r0 + 3 < n) {
        const float4* xp0 = Xq + (size_t)r0 * QK;
        const float4* xp1 = xp0 + QK;
        const float4* xp2 = xp1 + QK;
        const float4* xp3 = xp2 + QK;
#pragma unroll 4
        for (int k4 = 0; k4 < QK; ++k4) {
            const float4 x0 = xp0[k4];
            const float4 x1 = xp1[k4];
            const float4 x2 = xp2[k4];
            const float4 x3 = xp3[k4];
            const float4 w0 = Ws[(k4 * 4 + 0) * 16 + c4];
            const float4 w1 = Ws[(k4 * 4 + 1) * 16 + c4];
            const float4 w2 = Ws[(k4 * 4 + 2) * 16 + c4];
            const float4 w3 = Ws[(k4 * 4 + 3) * 16 + c4];
            fma4(a0, x0, w0, w1, w2, w3);
            fma4(a1, x1, w0, w1, w2, w3);
            fma4(a2, x2, w0, w1, w2, w3);
            fma4(a3, x3, w0, w1, w2, w3);
        }
        const float4 dv = ((const float4*)dinv)[r0 >> 2];
        scale4(a0, dv.x); scale4(a1, dv.y); scale4(a2, dv.z); scale4(a3, dv.w);
        ((float4*)HS)[(size_t)(r0 + 0) * 16 + c4] = a0;
        ((float4*)HS)[(size_t)(r0 + 1) * 16 + c4] = a1;
        ((float4*)HS)[(size_t)(r0 + 2) * 16 + c4] = a2;
        ((float4*)HS)[(size_t)(r0 + 3) * 16 + c4] = a3;
    } else {
        const float4 z = make_float4(0.f, 0.f, 0.f, 0.f);
        for (int k4 = 0; k4 < QK; ++k4) {
            const float4 x0 = (r0 + 0 < n) ? Xq[(size_t)(r0 + 0) * QK + k4] : z;
            const float4 x1 = (r0 + 1 < n) ? Xq[(size_t)(r0 + 1) * QK + k4] : z;
            const float4 x2 = (r0 + 2 < n) ? Xq[(size_t)(r0 + 2) * QK + k4] : z;
            const float4 x3 = (r0 + 3 < n) ? Xq[(size_t)(r0 + 3) * QK + k4] : z;
            const float4 w0 = Ws[(k4 * 4 + 0) * 16 + c4];
            const float4 w1 = Ws[(k4 * 4 + 1) * 16 + c4];
            const float4 w2 = Ws[(k4 * 4 + 2) * 16 + c4];
            const float4 w3 = Ws[(k4 * 4 + 3) * 16 + c4];
            fma4(a0, x0, w0, w1, w2, w3);
            fma4(a1, x1, w0, w1, w2, w3);
            fma4(a2, x2, w0, w1, w2, w3);
            fma4(a3, x3, w0, w1, w2, w3);
        }
        if (r0 + 0 < n) { scale4(a0, dinv[r0 + 0]); ((float4*)HS)[(size_t)(r0 + 0) * 16 + c4] = a0; }
        if (r0 + 1 < n) { scale4(a1, dinv[r0 + 1]); ((float4*)HS)[(size_t)(r0 + 1) * 16 + c4] = a1; }
        if (r0 + 2 < n) { scale4(a2, dinv[r0 + 2]); ((float4*)HS)[(size_t)(r0 + 2) * 16 + c4] = a2; }
        if (r0 + 3 < n) { scale4(a3, dinv[r0 + 3]); ((float4*)HS)[(size_t)(r0 + 3) * 16 + c4] = a3; }
    }
}

// ---------------------------------------------------------------------------
// k_gather: out[i] = dinv[i]*(sum_{j in N(i)} hs[j] + hs[i]) + b  (+ReLU)
// ---------------------------------------------------------------------------
template <bool RELU>
__global__ __launch_bounds__(256) void k_gather(const int* __restrict__ rowstart,
                                                const int* __restrict__ edata,
                                                const float* __restrict__ hs,
                                                const float* __restrict__ dinv,
                                                const float* __restrict__ bias,
                                                float* __restrict__ out) {
    int node = blockIdx.x * 16 + (threadIdx.x >> 4);
    int lane = threadIdx.x & 15;
    if (node >= N_NODES) return;

    int start = rowstart[node];
    int end   = rowstart[node + 1];

    float4 acc = make_float4(0.f, 0.f, 0.f, 0.f);
    for (int j = start; j < end; ++j) {
        int s = edata[j];
        const float4 v = *reinterpret_cast<const float4*>(&hs[(size_t)s * 64 + lane * 4]);
        acc.x += v.x;
        acc.y += v.y;
        acc.z += v.z;
        acc.w += v.w;
    }
    const float4 hv = *reinterpret_cast<const float4*>(&hs[(size_t)node * 64 + lane * 4]);
    acc.x += hv.x; acc.y += hv.y; acc.z += hv.z; acc.w += hv.w;

    const float di = dinv[node];
    const float4 bv = *reinterpret_cast<const float4*>(&bias[lane * 4]);
    acc.x = acc.x * di + bv.x;
    acc.y = acc.y * di + bv.y;
    acc.z = acc.z * di + bv.z;
    acc.w = acc.w * di + bv.w;
    if (RELU) {
        acc.x = fmaxf(acc.x, 0.f);
        acc.y = fmaxf(acc.y, 0.f);
        acc.z = fmaxf(acc.z, 0.f);
        acc.w = fmaxf(acc.w, 0.f);
    }
    *reinterpret_cast<float4*>(&out[(size_t)node * 64 + lane * 4]) = acc;
}

extern "C" void kernel_launch(void* const* d_in, const int* in_sizes, int n_in,
                              void* d_out, int out_size, void* d_ws, size_t ws_size,
                              hipStream_t stream) {
    const float* x  = (const float*)d_in[0];
    const int*   ei = (const int*)d_in[1];    // [2, N_EDGES] int32
    const float* W1 = (const float*)d_in[2];
    const float* b1 = (const float*)d_in[3];
    const float* W2 = (const float*)d_in[4];
    const float* b2 = (const float*)d_in[5];
    float* out = (float*)d_out;

    // Workspace carve-up (ints first; dinv/hs 16B-aligned):
    //   histT[NB*NPB] | bucketstart[NB+2] | brec[E] | rowstart[N+4] |
    //   edata[E] | dinv[N] | hs[N*64] | a1[N*64]   ~= 33 MB
    int*   histT       = (int*)d_ws;
    int*   bucketstart = histT + NB * NPB;                 // 25088
    int*   brec        = bucketstart + (NB + 2);           // +100
    int*   rowstart    = brec + N_EDGES;
    int*   edata       = rowstart + (N_NODES + 4);
    float* dinv        = (float*)(edata + N_EDGES);
    float* hs          = dinv + N_NODES;                   // offsets keep 16B align
    float* a1          = hs + (size_t)N_NODES * 64;

    // --- CSR build (counting-sort partition; no global float/random scatter) ---
    k_bhist<<<NPB, 256, 0, stream>>>(ei, histT);
    k_bscan<<<1, 256, 0, stream>>>(histT, bucketstart);
    k_part<<<NPB, 256, 0, stream>>>(ei, histT, brec);
    k_csr<<<NB, 256, 0, stream>>>(brec, bucketstart, rowstart, dinv, edata);

    // --- layer 1 ---
    k_gemm3<IN_DIM><<<(N_NODES + 63) / 64, 256, 0, stream>>>(x, W1, dinv, hs, N_NODES);
    k_gather<true><<<(N_NODES + 15) / 16, 256, 0, stream>>>(rowstart, edata, hs, dinv, b1, a1);

    // --- layer 2 ---
    k_gemm3<HID_DIM><<<(N_NODES + 63) / 64, 256, 0, stream>>>(a1, W2, dinv, hs, N_NODES);
    k_gather<false><<<(N_NODES + 15) / 16, 256, 0, stream>>>(rowstart, edata, hs, dinv, b2, out);
}

// Round 8
// 142.911 us; speedup vs baseline: 1.5783x; 1.2267x over previous
//
#include <hip/hip_runtime.h>
#include <stdint.h>

#define N_NODES 50000
#define N_EDGES 800000
#define IN_DIM  128
#define HID_DIM 64
#define OUT_DIM 64

#define NPB     256                         // partition blocks
#define EPB     (N_EDGES / NPB)             // 3125 edges per block (exact)
#define BSH     9                           // bucket shift: 512 nodes/bucket
#define NB      ((N_NODES + 511) >> BSH)    // 98 buckets

// ---------------------------------------------------------------------------
// bf16 helpers (RNE pack, bit-shift unpack; accumulate in fp32)
// ---------------------------------------------------------------------------
__device__ __forceinline__ uint32_t f2bf(float f) {
    uint32_t u = __float_as_uint(f);
    return (u + 0x7FFFu + ((u >> 16) & 1u)) >> 16;
}
__device__ __forceinline__ uint32_t pack2bf(float a, float b) {
    return f2bf(a) | (f2bf(b) << 16);
}
__device__ __forceinline__ float bflo(uint32_t v) { return __uint_as_float(v << 16); }
__device__ __forceinline__ float bfhi(uint32_t v) { return __uint_as_float(v & 0xFFFF0000u); }

// ---------------------------------------------------------------------------
// k_bhist: per-(block,bucket) histogram of dst. histT[bkt*NPB + blk].
// ---------------------------------------------------------------------------
__global__ __launch_bounds__(256) void k_bhist(const int* __restrict__ ei,
                                               int* __restrict__ histT) {
    __shared__ int hist[NB];
    const int blk = blockIdx.x, tid = threadIdx.x;
    if (tid < NB) hist[tid] = 0;
    __syncthreads();
    const int e0 = blk * EPB;
    for (int e = e0 + tid; e < e0 + EPB; e += 256)
        atomicAdd(&hist[ei[N_EDGES + e] >> BSH], 1);
    __syncthreads();
    if (tid < NB) histT[tid * NPB + blk] = hist[tid];
}

// ---------------------------------------------------------------------------
// k_bscan: single-block exclusive scan (in place) of histT[NB*NPB] in
// bucket-major order; emits bucketstart[NB+1].
// ---------------------------------------------------------------------------
__global__ __launch_bounds__(256) void k_bscan(int* __restrict__ histT,
                                               int* __restrict__ bucketstart) {
    const int t = threadIdx.x;
    const int CH = (NB * NPB) / 256;        // 98 contiguous elements per thread
    const int base = t * CH;
    int s = 0;
#pragma unroll 7
    for (int i = 0; i < CH; ++i) s += histT[base + i];

    int wid = t >> 6, lane = t & 63;
    int incl = s;
    for (int o = 1; o < 64; o <<= 1) {
        int v = __shfl_up(incl, o, 64);
        if (lane >= o) incl += v;
    }
    __shared__ int wt[4];
    if (lane == 63) wt[wid] = incl;
    __syncthreads();
    int woff = 0;
    for (int w = 0; w < wid; ++w) woff += wt[w];
    int excl = woff + incl - s;

#pragma unroll 7
    for (int i = 0; i < CH; ++i) {
        int v = histT[base + i];
        histT[base + i] = excl;
        excl += v;
    }
    __syncthreads();
    if (t < NB) bucketstart[t] = histT[t * NPB];
    if (t == 0) bucketstart[NB] = N_EDGES;
}

// ---------------------------------------------------------------------------
// k_part: re-stream edges; write rec = src | dlo<<16 into this block's
// reserved contiguous chunk of each bucket (coalesced-ish, XCD-friendly).
// ---------------------------------------------------------------------------
__global__ __launch_bounds__(256) void k_part(const int* __restrict__ ei,
                                              const int* __restrict__ histT,
                                              int* __restrict__ brec) {
    __shared__ int cursor[NB];
    const int blk = blockIdx.x, tid = threadIdx.x;
    if (tid < NB) cursor[tid] = histT[tid * NPB + blk];
    __syncthreads();
    const int e0 = blk * EPB;
    for (int e = e0 + tid; e < e0 + EPB; e += 256) {
        int s = ei[e];
        int d = ei[N_EDGES + e];
        int b = d >> BSH;
        int pos = atomicAdd(&cursor[b], 1);
        brec[pos] = s | ((d & 511) << 16);
    }
}

// ---------------------------------------------------------------------------
// k_csr: one block per bucket (512 nodes).  Counts per-node deg in LDS,
// block-scans to per-node offsets, emits rowstart & dinv (coalesced), then
// scatters final edata (src only) — whole CSR region written by ONE wg/XCD.
// ---------------------------------------------------------------------------
__global__ __launch_bounds__(256) void k_csr(const int* __restrict__ brec,
                                             const int* __restrict__ bucketstart,
                                             int* __restrict__ rowstart,
                                             float* __restrict__ dinv,
                                             int* __restrict__ edata) {
    __shared__ int deg[512];
    __shared__ int segoff[512];
    __shared__ int wt[4];
    const int b = blockIdx.x, tid = threadIdx.x;
    const int lo = b << BSH;
    const int cstart = bucketstart[b];
    const int cend   = bucketstart[b + 1];

    deg[tid] = 0;
    deg[tid + 256] = 0;
    __syncthreads();

    for (int j = cstart + tid; j < cend; j += 256)
        atomicAdd(&deg[brec[j] >> 16], 1);
    __syncthreads();

    const int i0 = tid << 1;
    const int d0 = deg[i0], d1 = deg[i0 + 1];
    const int s = d0 + d1;
    int wid = tid >> 6, lane = tid & 63;
    int incl = s;
    for (int o = 1; o < 64; o <<= 1) {
        int v = __shfl_up(incl, o, 64);
        if (lane >= o) incl += v;
    }
    if (lane == 63) wt[wid] = incl;
    __syncthreads();
    int woff = 0;
    for (int w = 0; w < wid; ++w) woff += wt[w];
    const int excl = woff + incl - s;

    segoff[i0]     = excl;
    segoff[i0 + 1] = excl + d0;

    if (lo + i0 < N_NODES) {
        rowstart[lo + i0] = cstart + excl;
        dinv[lo + i0] = rsqrtf((float)d0 + 1.0f);
    }
    if (lo + i0 + 1 < N_NODES) {
        rowstart[lo + i0 + 1] = cstart + excl + d0;
        dinv[lo + i0 + 1] = rsqrtf((float)d1 + 1.0f);
    }
    if (b == NB - 1 && tid == 0) rowstart[N_NODES] = cend;
    __syncthreads();

    for (int j = cstart + tid; j < cend; j += 256) {
        int rec = brec[j];
        int pos = cstart + atomicAdd(&segoff[rec >> 16], 1);
        edata[pos] = rec & 0xFFFF;
    }
}

// ---------------------------------------------------------------------------
// k_gemm3: HSB[n,64] (bf16) = (X[n,K] @ W[K,64]) * dinv[row].
// 64 rows x 64 cols per block; thread tile 4x4; only W staged in LDS; X read
// direct from global (16 same-address lanes merge). Epilogue packs bf16.
// ---------------------------------------------------------------------------
__device__ __forceinline__ void fma4(float4& acc, const float4& xv,
                                     const float4& w0, const float4& w1,
                                     const float4& w2, const float4& w3) {
    acc.x += xv.x * w0.x + xv.y * w1.x + xv.z * w2.x + xv.w * w3.x;
    acc.y += xv.x * w0.y + xv.y * w1.y + xv.z * w2.y + xv.w * w3.y;
    acc.z += xv.x * w0.z + xv.y * w1.z + xv.z * w2.z + xv.w * w3.z;
    acc.w += xv.x * w0.w + xv.y * w1.w + xv.z * w2.w + xv.w * w3.w;
}

__device__ __forceinline__ uint2 packbf4(const float4& a, float s) {
    return make_uint2(pack2bf(a.x * s, a.y * s), pack2bf(a.z * s, a.w * s));
}

template <int K>
__global__ __launch_bounds__(256) void k_gemm3(const float* __restrict__ X,
                                               const float* __restrict__ W,
                                               const float* __restrict__ dinv,
                                               uint32_t* __restrict__ HSB, int n) {
    constexpr int QK = K / 4;
    __shared__ float4 Ws[K * 16];
    const int tid = threadIdx.x;
    const int row0 = blockIdx.x * 64;

    for (int f = tid; f < K * 16; f += 256) Ws[f] = ((const float4*)W)[f];
    __syncthreads();

    const int c4 = tid & 15;
    const int r0 = row0 + ((tid >> 4) << 2);
    const float4* Xq = (const float4*)X;

    float4 a0 = make_float4(0.f, 0.f, 0.f, 0.f);
    float4 a1 = a0, a2 = a0, a3 = a0;

    if (r0 + 3 < n) {
        const float4* xp0 = Xq + (size_t)r0 * QK;
        const float4* xp1 = xp0 + QK;
        const float4* xp2 = xp1 + QK;
        const float4* xp3 = xp2 + QK;
#pragma unroll 4
        for (int k4 = 0; k4 < QK; ++k4) {
            const float4 x0 = xp0[k4];
            const float4 x1 = xp1[k4];
            const float4 x2 = xp2[k4];
            const float4 x3 = xp3[k4];
            const float4 w0 = Ws[(k4 * 4 + 0) * 16 + c4];
            const float4 w1 = Ws[(k4 * 4 + 1) * 16 + c4];
            const float4 w2 = Ws[(k4 * 4 + 2) * 16 + c4];
            const float4 w3 = Ws[(k4 * 4 + 3) * 16 + c4];
            fma4(a0, x0, w0, w1, w2, w3);
            fma4(a1, x1, w0, w1, w2, w3);
            fma4(a2, x2, w0, w1, w2, w3);
            fma4(a3, x3, w0, w1, w2, w3);
        }
        const float4 dv = ((const float4*)dinv)[r0 >> 2];
        // bf16 rows: 64 ushorts = 32 uints per row; thread writes 2 uints at c4*2
        ((uint2*)HSB)[((size_t)(r0 + 0) * 32 + c4 * 2) >> 1] = packbf4(a0, dv.x);
        ((uint2*)HSB)[((size_t)(r0 + 1) * 32 + c4 * 2) >> 1] = packbf4(a1, dv.y);
        ((uint2*)HSB)[((size_t)(r0 + 2) * 32 + c4 * 2) >> 1] = packbf4(a2, dv.z);
        ((uint2*)HSB)[((size_t)(r0 + 3) * 32 + c4 * 2) >> 1] = packbf4(a3, dv.w);
    } else {
        const float4 z = make_float4(0.f, 0.f, 0.f, 0.f);
        for (int k4 = 0; k4 < QK; ++k4) {
            const float4 x0 = (r0 + 0 < n) ? Xq[(size_t)(r0 + 0) * QK + k4] : z;
            const float4 x1 = (r0 + 1 < n) ? Xq[(size_t)(r0 + 1) * QK + k4] : z;
            const float4 x2 = (r0 + 2 < n) ? Xq[(size_t)(r0 + 2) * QK + k4] : z;
            const float4 x3 = (r0 + 3 < n) ? Xq[(size_t)(r0 + 3) * QK + k4] : z;
            const float4 w0 = Ws[(k4 * 4 + 0) * 16 + c4];
            const float4 w1 = Ws[(k4 * 4 + 1) * 16 + c4];
            const float4 w2 = Ws[(k4 * 4 + 2) * 16 + c4];
            const float4 w3 = Ws[(k4 * 4 + 3) * 16 + c4];
            fma4(a0, x0, w0, w1, w2, w3);
            fma4(a1, x1, w0, w1, w2, w3);
            fma4(a2, x2, w0, w1, w2, w3);
            fma4(a3, x3, w0, w1, w2, w3);
        }
        if (r0 + 0 < n) ((uint2*)HSB)[((size_t)(r0 + 0) * 32 + c4 * 2) >> 1] = packbf4(a0, dinv[r0 + 0]);
        if (r0 + 1 < n) ((uint2*)HSB)[((size_t)(r0 + 1) * 32 + c4 * 2) >> 1] = packbf4(a1, dinv[r0 + 1]);
        if (r0 + 2 < n) ((uint2*)HSB)[((size_t)(r0 + 2) * 32 + c4 * 2) >> 1] = packbf4(a2, dinv[r0 + 2]);
        if (r0 + 3 < n) ((uint2*)HSB)[((size_t)(r0 + 3) * 32 + c4 * 2) >> 1] = packbf4(a3, dinv[r0 + 3]);
    }
}

// ---------------------------------------------------------------------------
// k_gather: out[i] = dinv[i]*(sum_{j in N(i)} hs[j] + hs[i]) + b  (+ReLU)
// hs in bf16 (row = 32 uints = 128B). 8 lanes/node, 8 dims (1 uint4) each.
// ---------------------------------------------------------------------------
template <bool RELU>
__global__ __launch_bounds__(256) void k_gather(const int* __restrict__ rowstart,
                                                const int* __restrict__ edata,
                                                const uint32_t* __restrict__ hsb,
                                                const float* __restrict__ dinv,
                                                const float* __restrict__ bias,
                                                float* __restrict__ out) {
    int node = blockIdx.x * 32 + (threadIdx.x >> 3);
    int lane = threadIdx.x & 7;              // 8 lanes/node, 8 dims each
    if (node >= N_NODES) return;

    int start = rowstart[node];
    int end   = rowstart[node + 1];

    float a0 = 0.f, a1 = 0.f, a2 = 0.f, a3 = 0.f,
          a4 = 0.f, a5 = 0.f, a6 = 0.f, a7 = 0.f;
    const uint4* hq = (const uint4*)hsb;     // 16B = 8 bf16 dims
    const int lq = lane;                     // quad index within row (row = 8 uint4)

    for (int j = start; j < end; ++j) {
        int s = edata[j];
        const uint4 v = hq[(size_t)s * 8 + lq];
        a0 += bflo(v.x); a1 += bfhi(v.x);
        a2 += bflo(v.y); a3 += bfhi(v.y);
        a4 += bflo(v.z); a5 += bfhi(v.z);
        a6 += bflo(v.w); a7 += bfhi(v.w);
    }
    // self loop (hs already carries one dinv factor)
    {
        const uint4 v = hq[(size_t)node * 8 + lq];
        a0 += bflo(v.x); a1 += bfhi(v.x);
        a2 += bflo(v.y); a3 += bfhi(v.y);
        a4 += bflo(v.z); a5 += bfhi(v.z);
        a6 += bflo(v.w); a7 += bfhi(v.w);
    }

    const float di = dinv[node];
    const float4 b0 = *reinterpret_cast<const float4*>(&bias[lane * 8]);
    const float4 b1 = *reinterpret_cast<const float4*>(&bias[lane * 8 + 4]);
    float4 o0, o1;
    o0.x = a0 * di + b0.x;  o0.y = a1 * di + b0.y;
    o0.z = a2 * di + b0.z;  o0.w = a3 * di + b0.w;
    o1.x = a4 * di + b1.x;  o1.y = a5 * di + b1.y;
    o1.z = a6 * di + b1.z;  o1.w = a7 * di + b1.w;
    if (RELU) {
        o0.x = fmaxf(o0.x, 0.f); o0.y = fmaxf(o0.y, 0.f);
        o0.z = fmaxf(o0.z, 0.f); o0.w = fmaxf(o0.w, 0.f);
        o1.x = fmaxf(o1.x, 0.f); o1.y = fmaxf(o1.y, 0.f);
        o1.z = fmaxf(o1.z, 0.f); o1.w = fmaxf(o1.w, 0.f);
    }
    float4* op = (float4*)&out[(size_t)node * 64 + lane * 8];
    op[0] = o0;
    op[1] = o1;
}

extern "C" void kernel_launch(void* const* d_in, const int* in_sizes, int n_in,
                              void* d_out, int out_size, void* d_ws, size_t ws_size,
                              hipStream_t stream) {
    const float* x  = (const float*)d_in[0];
    const int*   ei = (const int*)d_in[1];    // [2, N_EDGES] int32
    const float* W1 = (const float*)d_in[2];
    const float* b1 = (const float*)d_in[3];
    const float* W2 = (const float*)d_in[4];
    const float* b2 = (const float*)d_in[5];
    float* out = (float*)d_out;

    // Workspace carve-up (16B-aligned chunks):
    //   histT[NB*NPB] | bucketstart[NB+2] | brec[E] | rowstart[N+4] |
    //   edata[E] | dinv[N] | hsb[N*32 uints] | a1[N*64 floats]
    int*      histT       = (int*)d_ws;
    int*      bucketstart = histT + NB * NPB;             // 25088
    int*      brec        = bucketstart + (NB + 2);       // +100
    int*      rowstart    = brec + N_EDGES;
    int*      edata       = rowstart + (N_NODES + 4);
    float*    dinv        = (float*)(edata + N_EDGES);
    uint32_t* hsb         = (uint32_t*)(dinv + N_NODES);  // bf16 [N][64] = N*32 uints
    float*    a1          = (float*)(hsb + (size_t)N_NODES * 32);

    // --- CSR build (counting-sort partition) ---
    k_bhist<<<NPB, 256, 0, stream>>>(ei, histT);
    k_bscan<<<1, 256, 0, stream>>>(histT, bucketstart);
    k_part<<<NPB, 256, 0, stream>>>(ei, histT, brec);
    k_csr<<<NB, 256, 0, stream>>>(brec, bucketstart, rowstart, dinv, edata);

    // --- layer 1 ---
    k_gemm3<IN_DIM><<<(N_NODES + 63) / 64, 256, 0, stream>>>(x, W1, dinv, hsb, N_NODES);
    k_gather<true><<<(N_NODES + 31) / 32, 256, 0, stream>>>(rowstart, edata, hsb, dinv, b1, a1);

    // --- layer 2 ---
    k_gemm3<HID_DIM><<<(N_NODES + 63) / 64, 256, 0, stream>>>(a1, W2, dinv, hsb, N_NODES);
    k_gather<false><<<(N_NODES + 31) / 32, 256, 0, stream>>>(rowstart, edata, hsb, dinv, b2, out);
}